// Round 2
// baseline (132.472 us; speedup 1.0000x reference)
//
#include <hip/hip_runtime.h>

#define LOG2E 1.4426950408889634f

__device__ __forceinline__ float fexp2(float x) {
#if __has_builtin(__builtin_amdgcn_exp2f)
    return __builtin_amdgcn_exp2f(x);   // v_exp_f32
#else
    return exp2f(x);
#endif
}

__device__ __forceinline__ float frcp(float x) {
#if __has_builtin(__builtin_amdgcn_rcpf)
    return __builtin_amdgcn_rcpf(x);    // v_rcp_f32
#else
    return 1.0f / x;
#endif
}

// ---------------------------------------------------------------------------
// Prep: fuse per-j constants into 8 floats (exp2-folded: -log2e premultiplied)
// coef[j*8 + {0..7}] = { nA0, nA1, nC, nT0, nT1, nTd, nTc, w' }
//   where w' = -log2e * cls_w[j]  (epilogue sigmoid folded into the weights)
// coef[512] = -log2e * cls_b
// Kept as a separate tiny kernel: main reads coef wave-uniformly via the
// scalar (s_load) pipe, free alongside VALU/trans.
// ---------------------------------------------------------------------------
__global__ void stgn_prep(const float* __restrict__ Wih_b,
                          const float* __restrict__ Wix_w,
                          const float* __restrict__ Wix_b,
                          const float* __restrict__ bi,
                          const float* __restrict__ WTh_b,
                          const float* __restrict__ WTx_w,
                          const float* __restrict__ WTx_b,
                          const float* __restrict__ WTt_w,
                          const float* __restrict__ WTt_b,
                          const float* __restrict__ bT,
                          const float* __restrict__ cls_w,
                          const float* __restrict__ cls_b,
                          float* __restrict__ coef) {
    int j = threadIdx.x;
    if (j < 64) {
        float nA0 = -LOG2E * Wix_w[2 * j];
        float nA1 = -LOG2E * Wix_w[2 * j + 1];
        float nC  = -LOG2E * (Wih_b[j] + Wix_b[j] + bi[j]);
        float nT0 = -LOG2E * WTx_w[2 * j];
        float nT1 = -LOG2E * WTx_w[2 * j + 1];
        float nTd = -LOG2E * WTt_w[j];
        float nTc = -LOG2E * (WTh_b[j] + WTx_b[j] + WTt_b[j] + bT[j]);
        float w   = -LOG2E * cls_w[j];
        float* c8 = coef + 8 * j;
        c8[0] = nA0; c8[1] = nA1; c8[2] = nC; c8[3] = nT0;
        c8[4] = nT1; c8[5] = nTd; c8[6] = nTc; c8[7] = w;
        if (j == 0) coef[512] = -LOG2E * cls_b[0];
    }
}

// ---------------------------------------------------------------------------
// Main: 1 batch element per thread. B = 524288 = 2048 blocks x 256 thr:
// 8 blocks/CU -> 32 waves/CU = 8 waves/SIMD (max occupancy). Previous 4-elem
// variant was grid-capped at 2 waves/SIMD, exposing trans/SMEM latency as
// issue bubbles (~8 cy/instr vs ~1.7 floor). bounds(256,8) caps VGPR at 64.
// Trans-pipe floor: 5 quarter-rate ops/j (3 exp2 + 2 rcp, irreducible).
//   a  = exp(-i_pre)          sig_i = 1/(1+a)
//   eT = exp(-T_pre)          sigT  = 1/(1+eT)
//   q  = exp(2*sigT*dt)       tanh_u = (q-1)/(q+1)
//   c  = sig_i*tanh_u = (q-1) / ((1+a)(1+q))   <- one shared rcp
//   h  = tanh(c) via endpoint-matched odd deg-9 poly (|c|<1, err<3e-4)
// ---------------------------------------------------------------------------
__global__ __launch_bounds__(256, 8) void stgn_main(const float* __restrict__ X,
                                                    const float* __restrict__ coef,
                                                    float* __restrict__ out,
                                                    int B) {
    int b = blockIdx.x * 256 + threadIdx.x;

    const float* xp = X + (size_t)b * 15 + 12;   // t=4: {x0, x1, dt}
    float2 x01 = *(const float2*)xp;             // bytes 48..56 of the 60B record
    float x0 = x01.x;
    float x1 = x01.y;
    float dt = xp[2];
    float dts2 = dt * (2.0f * LOG2E);

    const float k3 = -0.33333334f, k5 = 0.13333334f, k7 = -0.05396825f, k9 = 0.01556241f;

    float acc = 0.0f;

#pragma unroll 8
    for (int j = 0; j < 64; ++j) {
        const float* c8 = coef + 8 * j;   // wave-uniform -> s_load path
        float nA0 = c8[0], nA1 = c8[1], nC = c8[2];
        float nT0 = c8[3], nT1 = c8[4], nTd = c8[5], nTc = c8[6], w = c8[7];

        float a  = fexp2(fmaf(nA1, x1, fmaf(nA0, x0, nC)));
        float eT = fexp2(fmaf(nTd, dt, fmaf(nT1, x1, fmaf(nT0, x0, nTc))));
        float sigT = frcp(1.0f + eT);
        float q  = fexp2(dts2 * sigT);
        float r  = frcp((1.0f + a) * (1.0f + q));
        float c  = (q - 1.0f) * r;

        float c2 = c * c;
        float Q  = fmaf(c2, k9, k7);
        Q        = fmaf(c2, Q, k5);
        Q        = fmaf(c2, Q, k3);
        float th = fmaf(c * c2, Q, c);
        acc      = fmaf(w, th, acc);      // acc accumulates -log2e * (w . h)
    }

    // z' = -log2e*(h.w + cls_b); sigmoid(z) = 1/(1+2^z')
    float zp = acc + coef[512];
    out[b] = frcp(1.0f + fexp2(zp));
}

extern "C" void kernel_launch(void* const* d_in, const int* in_sizes, int n_in,
                              void* d_out, int out_size, void* d_ws, size_t ws_size,
                              hipStream_t stream) {
    // setup_inputs order:
    // 0:X_seq 1:Wfh_w 2:Wfh_b 3:Wfx_w 4:Wfx_b 5:bf 6:Wih_w 7:Wih_b 8:Wix_w
    // 9:Wix_b 10:bi 11:WTh_w 12:WTh_b 13:WTx_w 14:WTx_b 15:WTt_w 16:WTt_b
    // 17:bT 18:cls_w 19:cls_b
    const float* X = (const float*)d_in[0];
    float* coef = (float*)d_ws;

    stgn_prep<<<1, 64, 0, stream>>>(
        (const float*)d_in[7],   // Wih_b
        (const float*)d_in[8],   // Wix_w
        (const float*)d_in[9],   // Wix_b
        (const float*)d_in[10],  // bi
        (const float*)d_in[12],  // WTh_b
        (const float*)d_in[13],  // WTx_w
        (const float*)d_in[14],  // WTx_b
        (const float*)d_in[15],  // WTt_w
        (const float*)d_in[16],  // WTt_b
        (const float*)d_in[17],  // bT
        (const float*)d_in[18],  // cls_w
        (const float*)d_in[19],  // cls_b
        coef);

    int B = in_sizes[0] / 15;            // 524288
    int grid = B / 256;                  // 2048 blocks -> 8 blocks/CU
    stgn_main<<<grid, 256, 0, stream>>>(X, coef, (float*)d_out, B);
}

// Round 3
// 131.222 us; speedup vs baseline: 1.0095x; 1.0095x over previous
//
#include <hip/hip_runtime.h>

#define LOG2E 1.4426950408889634f

__device__ __forceinline__ float fexp2(float x) {
#if __has_builtin(__builtin_amdgcn_exp2f)
    return __builtin_amdgcn_exp2f(x);   // v_exp_f32
#else
    return exp2f(x);
#endif
}

__device__ __forceinline__ float frcp(float x) {
#if __has_builtin(__builtin_amdgcn_rcpf)
    return __builtin_amdgcn_rcpf(x);    // v_rcp_f32
#else
    return 1.0f / x;
#endif
}

// ---------------------------------------------------------------------------
// Single fused kernel. B = 524288 = 2048 blocks x 256 thr: 8 blocks/CU ->
// 32 waves/CU = 8 waves/SIMD (max occupancy). bounds(256,8) caps VGPR at 64.
//
// Prep is merged: threads 0..63 of each block fold the per-j constants into
// 8 floats in LDS (one-time, ~2KB; the 12 weight arrays are tiny and L2-hot
// after block 0). This removes the separate stgn_prep dispatch and the d_ws
// round-trip — the only remaining serial slack in the graph.
//
// scoef[j*8 + {0..7}] = { nA0, nA1, nC, nT0, nT1, nTd, nTc, w' }
//   (exp2-folded: -log2e premultiplied; w' = -log2e*cls_w, epilogue sigmoid
//    folded into the weights). scoef[512] = -log2e*cls_b.
//
// Hot-loop coef fetch: 2x wave-uniform broadcast ds_read_b128 per j
// (~16K cy/CU total) — hidden under the trans floor (see below).
//
// Pipe model per j per wave: 5 trans x 8cy = 40 cy (binding), ~19 VALU x 2cy
// = 38 cy. Trans floor per SIMD = 8 waves x 64 j x 40 = 20.5K cy = 8.5 us.
// The 5 quarter-rate ops (3 exp2 + 2 rcp) are algebraically irreducible:
//   a  = exp(-i_pre)          sig_i = 1/(1+a)
//   eT = exp(-T_pre)          sigT  = 1/(1+eT)
//   q  = exp(2*sigT*dt)       tanh_u = (q-1)/(q+1)
//   c  = sig_i*tanh_u = (q-1) / ((1+a)(1+q))   <- one shared rcp
//   h  = tanh(c) via endpoint-matched odd deg-9 poly (|c|<1, err<3e-4)
//     (poly kept over exp-form tanh: exp-form moves 14cy VALU -> 16cy trans,
//      and trans is the binding pipe)
// ---------------------------------------------------------------------------
__global__ __launch_bounds__(256, 8) void stgn_fused(const float* __restrict__ X,
                                                     const float* __restrict__ Wih_b,
                                                     const float* __restrict__ Wix_w,
                                                     const float* __restrict__ Wix_b,
                                                     const float* __restrict__ bi,
                                                     const float* __restrict__ WTh_b,
                                                     const float* __restrict__ WTx_w,
                                                     const float* __restrict__ WTx_b,
                                                     const float* __restrict__ WTt_w,
                                                     const float* __restrict__ WTt_b,
                                                     const float* __restrict__ bT,
                                                     const float* __restrict__ cls_w,
                                                     const float* __restrict__ cls_b,
                                                     float* __restrict__ out,
                                                     int B) {
    __shared__ __align__(16) float scoef[516];

    int tid = threadIdx.x;
    if (tid < 64) {
        int j = tid;
        float nA0 = -LOG2E * Wix_w[2 * j];
        float nA1 = -LOG2E * Wix_w[2 * j + 1];
        float nC  = -LOG2E * (Wih_b[j] + Wix_b[j] + bi[j]);
        float nT0 = -LOG2E * WTx_w[2 * j];
        float nT1 = -LOG2E * WTx_w[2 * j + 1];
        float nTd = -LOG2E * WTt_w[j];
        float nTc = -LOG2E * (WTh_b[j] + WTx_b[j] + WTt_b[j] + bT[j]);
        float w   = -LOG2E * cls_w[j];
        float* c8 = scoef + 8 * j;
        c8[0] = nA0; c8[1] = nA1; c8[2] = nC; c8[3] = nT0;
        c8[4] = nT1; c8[5] = nTd; c8[6] = nTc; c8[7] = w;
        if (j == 0) scoef[512] = -LOG2E * cls_b[0];
    }

    int b = blockIdx.x * 256 + tid;
    const float* xp = X + (size_t)b * 15 + 12;   // t=4: {x0, x1, dt}
    float2 x01 = *(const float2*)xp;             // bytes 48..56 of the 60B record
    float x0 = x01.x;
    float x1 = x01.y;
    float dt = xp[2];
    float dts2 = dt * (2.0f * LOG2E);

    __syncthreads();

    const float k3 = -0.33333334f, k5 = 0.13333334f, k7 = -0.05396825f, k9 = 0.01556241f;

    float acc = 0.0f;

#pragma unroll 8
    for (int j = 0; j < 64; ++j) {
        const float* c8 = scoef + 8 * j;   // wave-uniform -> broadcast ds_read_b128 x2
        float4 cA = *(const float4*)c8;
        float4 cB = *(const float4*)(c8 + 4);
        float nA0 = cA.x, nA1 = cA.y, nC = cA.z, nT0 = cA.w;
        float nT1 = cB.x, nTd = cB.y, nTc = cB.z, w = cB.w;

        float a  = fexp2(fmaf(nA1, x1, fmaf(nA0, x0, nC)));
        float eT = fexp2(fmaf(nTd, dt, fmaf(nT1, x1, fmaf(nT0, x0, nTc))));
        float sigT = frcp(1.0f + eT);
        float q  = fexp2(dts2 * sigT);
        float r  = frcp((1.0f + a) * (1.0f + q));
        float c  = (q - 1.0f) * r;

        float c2 = c * c;
        float Q  = fmaf(c2, k9, k7);
        Q        = fmaf(c2, Q, k5);
        Q        = fmaf(c2, Q, k3);
        float th = fmaf(c * c2, Q, c);
        acc      = fmaf(w, th, acc);      // acc accumulates -log2e * (w . h)
    }

    // z' = -log2e*(h.w + cls_b); sigmoid(z) = 1/(1+2^z')
    float zp = acc + scoef[512];
    out[b] = frcp(1.0f + fexp2(zp));
}

extern "C" void kernel_launch(void* const* d_in, const int* in_sizes, int n_in,
                              void* d_out, int out_size, void* d_ws, size_t ws_size,
                              hipStream_t stream) {
    // setup_inputs order:
    // 0:X_seq 1:Wfh_w 2:Wfh_b 3:Wfx_w 4:Wfx_b 5:bf 6:Wih_w 7:Wih_b 8:Wix_w
    // 9:Wix_b 10:bi 11:WTh_w 12:WTh_b 13:WTx_w 14:WTx_b 15:WTt_w 16:WTt_b
    // 17:bT 18:cls_w 19:cls_b
    const float* X = (const float*)d_in[0];

    int B = in_sizes[0] / 15;            // 524288
    int grid = B / 256;                  // 2048 blocks -> 8 blocks/CU

    stgn_fused<<<grid, 256, 0, stream>>>(
        X,
        (const float*)d_in[7],   // Wih_b
        (const float*)d_in[8],   // Wix_w
        (const float*)d_in[9],   // Wix_b
        (const float*)d_in[10],  // bi
        (const float*)d_in[12],  // WTh_b
        (const float*)d_in[13],  // WTx_w
        (const float*)d_in[14],  // WTx_b
        (const float*)d_in[15],  // WTt_w
        (const float*)d_in[16],  // WTt_b
        (const float*)d_in[17],  // bT
        (const float*)d_in[18],  // cls_w
        (const float*)d_in[19],  // cls_b
        (float*)d_out, B);
}